// Round 2
// baseline (1557.779 us; speedup 1.0000x reference)
//
#include <hip/hip_runtime.h>
#include <stdint.h>

typedef unsigned short u16;
typedef __bf16 bf16x8 __attribute__((ext_vector_type(8)));
typedef unsigned short u16x8 __attribute__((ext_vector_type(8)));
typedef float f32x4 __attribute__((ext_vector_type(4)));

#define AS1 __attribute__((address_space(1)))
#define AS3 __attribute__((address_space(3)))

static constexpr int    NR = 16384;                  // B*S rows
static constexpr int    RS = 3072;                   // row stride = M*DM
static constexpr size_t WT_ELEMS  = (size_t)12 << 20;      // 12 * 1M bf16
static constexpr size_t ACT_ELEMS = (size_t)NR * RS;       // 50331648

__device__ __forceinline__ u16 f2b(float f) {
  unsigned u = __builtin_bit_cast(unsigned, f);
  return (u16)((u + 0x7FFFu + ((u >> 16) & 1u)) >> 16);   // RNE
}
__device__ __forceinline__ float b2f(u16 b) {
  return __builtin_bit_cast(float, ((unsigned)b) << 16);
}
__device__ __forceinline__ void gload16(const u16* g, u16* l) {
  __builtin_amdgcn_global_load_lds((const AS1 unsigned int*)g,
                                   (AS3 unsigned int*)l, 16, 0, 0);
}

// ---------- fp32 -> bf16 bulk convert (grid exact: 8 elems/thread) ----------
__global__ __launch_bounds__(256) void f32_to_bf16_k(
    const float* __restrict__ in, u16* __restrict__ out) {
  size_t i = ((size_t)blockIdx.x * 256 + threadIdx.x) * 8;
  f32x4 a = *(const f32x4*)(in + i);
  f32x4 b = *(const f32x4*)(in + i + 4);
  u16x8 o;
  o[0] = f2b(a[0]); o[1] = f2b(a[1]); o[2] = f2b(a[2]); o[3] = f2b(a[3]);
  o[4] = f2b(b[0]); o[5] = f2b(b[1]); o[6] = f2b(b[2]); o[7] = f2b(b[3]);
  *(u16x8*)(out + i) = o;
}

// ---------- weight convert + transpose: Wt[z][e][d] = W[t][m][d][e] ----------
__global__ __launch_bounds__(256) void wt_conv_k(
    const float* __restrict__ Wq, const float* __restrict__ Wk,
    const float* __restrict__ Wv, const float* __restrict__ Wo,
    u16* __restrict__ Wt) {
  int z = blockIdx.z;
  int t = z / 3, m = z % 3;
  const float* src = (t == 0) ? Wq : (t == 1) ? Wk : (t == 2) ? Wv : Wo;
  src += (size_t)m << 20;
  u16* dst = Wt + ((size_t)z << 20);
  __shared__ float tile[32][33];
  int tx = threadIdx.x & 31, ty = threadIdx.x >> 5;  // ty: 0..7
  int d0 = blockIdx.y * 32, e0 = blockIdx.x * 32;
#pragma unroll
  for (int i = 0; i < 4; ++i)
    tile[ty + i * 8][tx] = src[(size_t)(d0 + ty + i * 8) * 1024 + e0 + tx];
  __syncthreads();
#pragma unroll
  for (int i = 0; i < 4; ++i)
    dst[(size_t)(e0 + ty + i * 8) * 1024 + d0 + tx] = f2b(tile[tx][ty + i * 8]);
}

// ---------- GEMM: C[r][m*1024+e] = sum_d A[r][m*1024+d] * W[m][d][e] + bias[m][e]
// A: bf16 [16384][3072]; Wt: bf16 [3][1024(e)][1024(d)] (transposed weights);
// C: bf16 ws tensor (OUT_FP32=0) or fp32 d_out (OUT_FP32=1), both stride 3072.
// 128x128 tile, BK=32, 4 waves (2x2 of 64x64), 16x16x32 bf16 MFMA.
// LDS tiles are [128 rows][4 chunks of 16B]; chunk ^= (row>>1)&3 swizzle applied
// to BOTH the global staging source and the ds_read (rule #21).
template <int OUT_FP32>
__global__ __launch_bounds__(256) void gemm_bt(
    const u16* __restrict__ A, const u16* __restrict__ Wt,
    const float* __restrict__ bias, void* __restrict__ C) {
  const int m = blockIdx.z;
  const int colBase = blockIdx.x * 128;
  const int rowBase = blockIdx.y * 128;
  const int cOff = m << 10;
  const u16* B = Wt + ((size_t)m << 20);

  __shared__ u16 Alds[128 * 32];
  __shared__ u16 Blds[128 * 32];

  const int tid = threadIdx.x;
  const int lane = tid & 63;
  const int wid = tid >> 6;
  const int wr = (wid >> 1) * 64;   // wave row offset in tile
  const int wc = (wid & 1) * 64;    // wave col offset in tile
  const int lrow = lane & 15;
  const int kg = lane >> 4;

  // staging: two 1KB global_load_lds per wave per operand per K-step
  const int gl0 = wid * 128 + lane;        // it = 0
  const int gl1 = wid * 128 + 64 + lane;   // it = 1
  const int r0 = gl0 >> 2, c0 = (gl0 & 3) ^ ((r0 >> 1) & 3);
  const int r1 = gl1 >> 2, c1 = (gl1 & 3) ^ ((r1 >> 1) & 3);

  const u16* aSrc0 = A + (size_t)(rowBase + r0) * RS + cOff + c0 * 8;
  const u16* aSrc1 = A + (size_t)(rowBase + r1) * RS + cOff + c1 * 8;
  const u16* bSrc0 = B + (size_t)(colBase + r0) * 1024 + c0 * 8;
  const u16* bSrc1 = B + (size_t)(colBase + r1) * 1024 + c1 * 8;
  u16* aDst0 = &Alds[(wid * 2 + 0) * 512];
  u16* aDst1 = &Alds[(wid * 2 + 1) * 512];
  u16* bDst0 = &Blds[(wid * 2 + 0) * 512];
  u16* bDst1 = &Blds[(wid * 2 + 1) * 512];

  // fragment LDS offsets (u16 units), swizzled
  int aoff[4], boff[4];
#pragma unroll
  for (int i = 0; i < 4; ++i) {
    int ar = wr + i * 16 + lrow;
    aoff[i] = ar * 32 + (kg ^ ((ar >> 1) & 3)) * 8;
    int br = wc + i * 16 + lrow;
    boff[i] = br * 32 + (kg ^ ((br >> 1) & 3)) * 8;
  }

  f32x4 acc[4][4];
#pragma unroll
  for (int i = 0; i < 4; ++i)
#pragma unroll
    for (int n = 0; n < 4; ++n) acc[i][n] = (f32x4)0.f;

#pragma unroll 1
  for (int kk = 0; kk < 1024; kk += 32) {
    gload16(aSrc0 + kk, aDst0);
    gload16(aSrc1 + kk, aDst1);
    gload16(bSrc0 + kk, bDst0);
    gload16(bSrc1 + kk, bDst1);
    __syncthreads();  // drains vmcnt -> LDS tiles ready
    bf16x8 af[4], bfv[4];
#pragma unroll
    for (int i = 0; i < 4; ++i)
      af[i] = __builtin_bit_cast(bf16x8, *(const u16x8*)&Alds[aoff[i]]);
#pragma unroll
    for (int n = 0; n < 4; ++n)
      bfv[n] = __builtin_bit_cast(bf16x8, *(const u16x8*)&Blds[boff[n]]);
#pragma unroll
    for (int i = 0; i < 4; ++i)
#pragma unroll
      for (int n = 0; n < 4; ++n)
        acc[i][n] =
            __builtin_amdgcn_mfma_f32_16x16x32_bf16(af[i], bfv[n], acc[i][n], 0, 0, 0);
    __syncthreads();  // all waves done reading before next stage
  }

  // epilogue: C/D frag layout col=lane&15, row=(lane>>4)*4+q (m89-verified)
#pragma unroll
  for (int n = 0; n < 4; ++n) {
    int e = colBase + wc + n * 16 + lrow;
    float bs = bias[(m << 10) + e];
#pragma unroll
    for (int i = 0; i < 4; ++i) {
      int rr = rowBase + wr + i * 16 + kg * 4;
#pragma unroll
      for (int q = 0; q < 4; ++q) {
        float v = acc[i][n][q] + bs;
        size_t off = (size_t)(rr + q) * RS + cOff + e;
        if constexpr (OUT_FP32)
          ((float*)C)[off] = v;
        else
          ((u16*)C)[off] = f2b(v);
      }
    }
  }
}

// ---------- modal attention: one wave per (row, head) ----------
__global__ __launch_bounds__(256) void attn_modal(
    const u16* __restrict__ Qb, const u16* __restrict__ Kb,
    const u16* __restrict__ Vb, u16* __restrict__ Xb) {
  int gw = (blockIdx.x << 2) + (threadIdx.x >> 6);  // global wave id
  int lane = threadIdx.x & 63;                      // = d within head
  int r = gw >> 4, h = gw & 15;
  size_t base = (size_t)r * RS + (h << 6) + lane;
  float q[3], k[3], v[3];
#pragma unroll
  for (int mm = 0; mm < 3; ++mm) {
    q[mm] = b2f(Qb[base + (mm << 10)]);
    k[mm] = b2f(Kb[base + (mm << 10)]);
    v[mm] = b2f(Vb[base + (mm << 10)]);
  }
  float s[9];
#pragma unroll
  for (int i = 0; i < 3; ++i)
#pragma unroll
    for (int j = 0; j < 3; ++j) s[3 * i + j] = q[i] * k[j];
#pragma unroll
  for (int off = 1; off < 64; off <<= 1) {
#pragma unroll
    for (int t = 0; t < 9; ++t) s[t] += __shfl_xor(s[t], off, 64);
  }
#pragma unroll
  for (int i = 0; i < 3; ++i) {
    float a0 = s[3 * i] * 0.125f, a1 = s[3 * i + 1] * 0.125f,
          a2 = s[3 * i + 2] * 0.125f;
    float mx = fmaxf(fmaxf(a0, a1), a2);
    float e0 = __expf(a0 - mx), e1 = __expf(a1 - mx), e2 = __expf(a2 - mx);
    float inv = 1.0f / (e0 + e1 + e2);
    float x = (e0 * v[0] + e1 * v[1] + e2 * v[2]) * inv;
    Xb[base + (i << 10)] = f2b(x);  // X[r][m=i][h*64+d]
  }
}

extern "C" void kernel_launch(void* const* d_in, const int* in_sizes, int n_in,
                              void* d_out, int out_size, void* d_ws,
                              size_t ws_size, hipStream_t stream) {
  const float* query = (const float*)d_in[0];
  const float* key   = (const float*)d_in[1];
  const float* value = (const float*)d_in[2];
  const float* Wq = (const float*)d_in[3];
  const float* bq = (const float*)d_in[4];
  const float* Wk = (const float*)d_in[5];
  const float* bk = (const float*)d_in[6];
  const float* Wv = (const float*)d_in[7];
  const float* bv = (const float*)d_in[8];
  const float* Wo = (const float*)d_in[9];
  const float* bo = (const float*)d_in[10];

  // ws layout (u16 elems): Wt | Qb | Kb | Vb | Act(=X)
  size_t need = (WT_ELEMS + 4 * ACT_ELEMS) * sizeof(u16);  // 427,819,008 B
  if (ws_size < need) return;  // learn ws_size from the failure if too small

  u16* Wt  = (u16*)d_ws;
  u16* Qb  = Wt + WT_ELEMS;
  u16* Kb  = Qb + ACT_ELEMS;
  u16* Vb  = Kb + ACT_ELEMS;
  u16* Act = Vb + ACT_ELEMS;  // activation staging; reused as attention out X

  dim3 thr(256);
  wt_conv_k<<<dim3(32, 32, 12), thr, 0, stream>>>(Wq, Wk, Wv, Wo, Wt);

  const float* acts[3]  = {query, key, value};
  const float* biass[3] = {bq, bk, bv};
  u16* outs[3] = {Qb, Kb, Vb};
  for (int t = 0; t < 3; ++t) {
    f32_to_bf16_k<<<24576, thr, 0, stream>>>(acts[t], Act);
    gemm_bt<0><<<dim3(8, 128, 3), thr, 0, stream>>>(
        Act, Wt + (size_t)t * 3 * 1048576, biass[t], outs[t]);
  }

  attn_modal<<<65536, thr, 0, stream>>>(Qb, Kb, Vb, Act);

  gemm_bt<1><<<dim3(8, 128, 3), thr, 0, stream>>>(
      Act, Wt + (size_t)9 * 1048576, bo, d_out);
}